// Round 2
// baseline (7273.000 us; speedup 1.0000x reference)
//
#include <hip/hip_runtime.h>

#define INPUT 64
#define HID 256
#define BATCH 128
#define TSTEPS 1000
#define KTOT 320            // 256 (h) + 64 (x)
#define NCH 4               // h-split chunks per group
#define CHW 64              // h columns per chunk

typedef __bf16 bf16_t;
typedef __bf16 bf16x8 __attribute__((ext_vector_type(8)));
typedef float  f32x4  __attribute__((ext_vector_type(4)));

// ---- ws layout (bytes) ----
#define WPACK_OFF   0
#define WPACK_BYTES (1024 * KTOT * 2)            // 655360
#define BIAS_OFF    (WPACK_OFF + WPACK_BYTES)
#define BIAS_BYTES  (1024 * 4)
#define EXCH_OFF    (BIAS_OFF + BIAS_BYTES)      // 32 slots x 2 parity x 16x64 bf16
#define EXCH_BYTES  (32 * 2 * 1024 * 2)
#define FLAG_OFF    (EXCH_OFF + EXCH_BYTES)      // 32 flags, 64B apart

__global__ void lstm_prep(
    const float* __restrict__ Wii, const float* __restrict__ Wif,
    const float* __restrict__ Wig, const float* __restrict__ Wio,
    const float* __restrict__ Whi, const float* __restrict__ Whf,
    const float* __restrict__ Whg, const float* __restrict__ Who,
    const float* __restrict__ bii, const float* __restrict__ bif,
    const float* __restrict__ big, const float* __restrict__ bio,
    const float* __restrict__ bhi, const float* __restrict__ bhf,
    const float* __restrict__ bhg, const float* __restrict__ bho,
    bf16_t* __restrict__ wpack, float* __restrict__ bias,
    int* __restrict__ flags)
{
    int id = blockIdx.x * 256 + threadIdx.x;
    if (id < 1024 * KTOT) {
        int n = id / KTOT, k = id % KTOT;
        int g = n >> 8, j = n & 255;
        const float* Wh = (g == 0) ? Whi : (g == 1) ? Whf : (g == 2) ? Whg : Who;
        const float* Wi = (g == 0) ? Wii : (g == 1) ? Wif : (g == 2) ? Wig : Wio;
        float v = (k < HID) ? Wh[j * HID + k] : Wi[j * INPUT + (k - HID)];
        wpack[id] = (bf16_t)v;
    }
    if (id < 1024) {
        int g = id >> 8, j = id & 255;
        const float* bi = (g == 0) ? bii : (g == 1) ? bif : (g == 2) ? big : bio;
        const float* bh = (g == 0) ? bhi : (g == 1) ? bhf : (g == 2) ? bhg : bho;
        bias[id] = bi[j] + bh[j];
    }
    if (id < 32) flags[id * 16] = 0;
}

__device__ __forceinline__ float sigmoid_f(float v) {
    return 1.0f / (1.0f + __expf(-v));
}
__device__ __forceinline__ float tanh_f(float v) {
    return 1.0f - 2.0f / (__expf(2.0f * v) + 1.0f);
}

// 32 blocks: group = blockIdx&7 (same XCD for a group), chunk = blockIdx>>3
__global__ __launch_bounds__(256, 1) void lstm_main(
    const float* __restrict__ x, const bf16_t* __restrict__ wpack,
    const float* __restrict__ bias_g, float* __restrict__ out,
    bf16_t* __restrict__ exch, int* __restrict__ flags)
{
    __shared__ bf16_t hx[16 * 72];       // own h chunk: [16][64] pad->72
    __shared__ bf16_t xb[2 * 16 * 72];   // x stage dbuf: [2][16][64] pad->72

    const int bid   = blockIdx.x;
    const int group = bid & 7;
    const int chunk = bid >> 3;
    const int tid   = threadIdx.x;
    const int w     = tid >> 6;          // wave 0..3
    const int l     = tid & 63;
    const int col   = l & 15;
    const int kb    = l >> 4;            // 0..3

    const int jloc  = w * 16 + col;            // 0..63 within chunk
    const int jglob = chunk * CHW + jloc;      // 0..255

    // ---- persistent weights: 4 gates x 10 K-slices, register-pinned ----
    f32x4 bW[4][10];
#pragma unroll
    for (int gt = 0; gt < 4; ++gt) {
        const bf16_t* wrow = wpack + (size_t)(gt * 256 + jglob) * KTOT;
#pragma unroll
        for (int ks = 0; ks < 10; ++ks)
            bW[gt][ks] = *(const f32x4*)(wrow + ks * 32 + kb * 8);
    }
#pragma unroll
    for (int gt = 0; gt < 4; ++gt)
#pragma unroll
        for (int ks = 0; ks < 10; ++ks)
            asm volatile("" : "+v"(bW[gt][ks]));   // forbid re-sinking into the loop

    float bias_r[4];
#pragma unroll
    for (int gt = 0; gt < 4; ++gt) bias_r[gt] = bias_g[gt * 256 + jglob];

    float c_st[4] = {0.f, 0.f, 0.f, 0.f};

    const int slot = (group << 2) | chunk;
    int* flag_me = flags + slot * 16;

    // prologue: stage x_0 into xb parity 0
    {
        int b = tid >> 4, i0 = (tid & 15) * 4;
        float4 v = *(const float4*)(x + (size_t)(group * 16 + b) * (TSTEPS * INPUT) + i0);
        bf16_t* d = xb + b * 72 + i0;
        d[0] = (bf16_t)v.x; d[1] = (bf16_t)v.y; d[2] = (bf16_t)v.z; d[3] = (bf16_t)v.w;
    }

    for (int t = 0; t < TSTEPS; ++t) {
        __syncthreads();                                   // (1) x_t staged, hx ready
        const int par = t & 1;

        f32x4 acc[4];
#pragma unroll
        for (int gt = 0; gt < 4; ++gt)
            acc[gt] = (f32x4){bias_r[gt], bias_r[gt], bias_r[gt], bias_r[gt]};

        // x-part (K slices 8,9)
        {
            const bf16_t* xrow = xb + par * 1152 + col * 72 + kb * 8;
            bf16x8 a0 = *(const bf16x8*)(xrow);
            bf16x8 a1 = *(const bf16x8*)(xrow + 32);
#pragma unroll
            for (int gt = 0; gt < 4; ++gt) {
                acc[gt] = __builtin_amdgcn_mfma_f32_16x16x32_bf16(a0, __builtin_bit_cast(bf16x8, bW[gt][8]), acc[gt], 0, 0, 0);
                acc[gt] = __builtin_amdgcn_mfma_f32_16x16x32_bf16(a1, __builtin_bit_cast(bf16x8, bW[gt][9]), acc[gt], 0, 0, 0);
            }
        }
        // own h chunk (K slices 2*chunk, 2*chunk+1)
        if (t > 0) {
            const bf16_t* hrow = hx + col * 72 + kb * 8;
            bf16x8 h0 = *(const bf16x8*)(hrow);
            bf16x8 h1 = *(const bf16x8*)(hrow + 32);
#pragma unroll
            for (int gt = 0; gt < 4; ++gt) {
                acc[gt] = __builtin_amdgcn_mfma_f32_16x16x32_bf16(h0, __builtin_bit_cast(bf16x8, bW[gt][2 * chunk]), acc[gt], 0, 0, 0);
                acc[gt] = __builtin_amdgcn_mfma_f32_16x16x32_bf16(h1, __builtin_bit_cast(bf16x8, bW[gt][2 * chunk + 1]), acc[gt], 0, 0, 0);
            }
        }
        // stage x_{t+1} into other parity (hides HBM/L2 latency under exchange)
        if (t + 1 < TSTEPS) {
            int b = tid >> 4, i0 = (tid & 15) * 4;
            float4 v = *(const float4*)(x + (size_t)(group * 16 + b) * (TSTEPS * INPUT) + (size_t)(t + 1) * INPUT + i0);
            bf16_t* d = xb + (par ^ 1) * 1152 + b * 72 + i0;
            d[0] = (bf16_t)v.x; d[1] = (bf16_t)v.y; d[2] = (bf16_t)v.z; d[3] = (bf16_t)v.w;
        }
        // partner chunks (3x, via L2 exchange)
        if (t > 0) {
            if (tid < 3) {
                int pc = (chunk + 1 + tid) & NCH - 1;
                int ps = (group << 2) | pc;
                while (__hip_atomic_load(flags + ps * 16, __ATOMIC_ACQUIRE, __HIP_MEMORY_SCOPE_AGENT) < t) {}
            }
            __syncthreads();                               // (2) partner h_{t-1} visible; hx reads done
#pragma unroll
            for (int q = 0; q < 3; ++q) {
                int pc = (chunk + 1 + q) & (NCH - 1);
                int ps = (group << 2) | pc;
                const bf16_t* bufR = exch + ((size_t)ps * 2 + ((t - 1) & 1)) * 1024;
                bf16x8 p0 = *(const bf16x8*)(bufR + col * 64 + kb * 8);
                bf16x8 p1 = *(const bf16x8*)(bufR + col * 64 + 32 + kb * 8);
#pragma unroll
                for (int gt = 0; gt < 4; ++gt) {
                    acc[gt] = __builtin_amdgcn_mfma_f32_16x16x32_bf16(p0, __builtin_bit_cast(bf16x8, bW[gt][2 * pc]), acc[gt], 0, 0, 0);
                    acc[gt] = __builtin_amdgcn_mfma_f32_16x16x32_bf16(p1, __builtin_bit_cast(bf16x8, bW[gt][2 * pc + 1]), acc[gt], 0, 0, 0);
                }
            }
        }

        // epilogue: gates -> c,h ; publish h; out-stores AFTER the flag release
        bf16_t* bufW = exch + ((size_t)slot * 2 + par) * 1024;
        float hv[4];
#pragma unroll
        for (int r = 0; r < 4; ++r) {
            int be = kb * 4 + r;                           // batch row in group
            float gi = sigmoid_f(acc[0][r]);
            float gf = sigmoid_f(acc[1][r]);
            float gg = tanh_f(acc[2][r]);
            float go = sigmoid_f(acc[3][r]);
            float c  = gf * c_st[r] + gi * gg;
            c_st[r]  = c;
            float h  = go * tanh_f(c);
            hv[r]    = h;
            bf16_t hb = (bf16_t)h;
            hx[be * 72 + jloc]   = hb;                     // own A for next step
            bufW[be * 64 + jloc] = hb;                     // partners' A for next step
        }
        __syncthreads();                                   // (3) exch/hx stores drained
        if (tid == 0)
            __hip_atomic_store(flag_me, t + 1, __ATOMIC_RELEASE, __HIP_MEMORY_SCOPE_AGENT);
#pragma unroll
        for (int r = 0; r < 4; ++r) {
            int bg = group * 16 + kb * 4 + r;
            out[((size_t)bg * TSTEPS + t) * HID + jglob] = hv[r];
            if (t == TSTEPS - 1) {
                out[(size_t)BATCH * TSTEPS * HID + (size_t)bg * HID + jglob] = hv[r];
                out[(size_t)BATCH * TSTEPS * HID + (size_t)BATCH * HID + (size_t)bg * HID + jglob] = c_st[r];
            }
        }
    }
}

extern "C" void kernel_launch(void* const* d_in, const int* in_sizes, int n_in,
                              void* d_out, int out_size, void* d_ws, size_t ws_size,
                              hipStream_t stream)
{
    (void)in_sizes; (void)n_in; (void)out_size; (void)ws_size;
    const float* x   = (const float*)d_in[0];
    const float* Wii = (const float*)d_in[1];
    const float* bii = (const float*)d_in[2];
    const float* Wif = (const float*)d_in[3];
    const float* bif = (const float*)d_in[4];
    const float* Wig = (const float*)d_in[5];
    const float* big = (const float*)d_in[6];
    const float* Wio = (const float*)d_in[7];
    const float* bio = (const float*)d_in[8];
    const float* Whi = (const float*)d_in[9];
    const float* bhi = (const float*)d_in[10];
    const float* Whf = (const float*)d_in[11];
    const float* bhf = (const float*)d_in[12];
    const float* Whg = (const float*)d_in[13];
    const float* bhg = (const float*)d_in[14];
    const float* Who = (const float*)d_in[15];
    const float* bho = (const float*)d_in[16];

    char* ws = (char*)d_ws;
    bf16_t* wpack = (bf16_t*)(ws + WPACK_OFF);
    float*  bias  = (float*)(ws + BIAS_OFF);
    bf16_t* exch  = (bf16_t*)(ws + EXCH_OFF);
    int*    flags = (int*)(ws + FLAG_OFF);

    lstm_prep<<<(1024 * KTOT + 255) / 256, 256, 0, stream>>>(
        Wii, Wif, Wig, Wio, Whi, Whf, Whg, Who,
        bii, bif, big, bio, bhi, bhf, bhg, bho,
        wpack, bias, flags);

    lstm_main<<<32, 256, 0, stream>>>(
        x, wpack, bias, (float*)d_out, exch, flags);
}